// Round 5
// baseline (872.209 us; speedup 1.0000x reference)
//
#include <hip/hip_runtime.h>

typedef __bf16 bf16;
typedef __attribute__((ext_vector_type(4))) __bf16 bf16x4;
typedef __attribute__((ext_vector_type(8))) __bf16 bf16x8;
typedef __attribute__((ext_vector_type(4))) float f32x4;

#define MFMA(A,B,C) __builtin_amdgcn_mfma_f32_16x16x32_bf16(A,B,C,0,0,0)

#define SEQ 2048
#define EMB 512
#define HD  64
#define SCALE 22.627416997969522f  // sqrt(512): scores are divided by E^-0.5
// Online-softmax seed: not -inf (fast-math folds inf constants to poison).
#define NEG_SEED -3.0e4f

// ---------------------------------------------------------------------------
// QKV projection: C[M,N] = x[M,512] @ W[N,512]^T + b[n], fp32 in.
// Both operands hi/lo-split at LDS staging; 3 MFMAs (xh*Wh + xl*Wh + xh*Wl)
// give ~17-bit effective input precision (scores are amplified by sqrt(512)).
// Epilogue splits columns into Qh/Ql (pre-scaled), Kh/Kl, V^T [bh][d][s].
// grid (128, 24), block 256 (4 waves, 2x2 grid of 32x32)
// ---------------------------------------------------------------------------
__global__ __launch_bounds__(256)
void gemm_qkv(const float* __restrict__ A, const float* __restrict__ Bm,
              const float* __restrict__ bias,
              bf16* __restrict__ Qh, bf16* __restrict__ Ql,
              bf16* __restrict__ Kh, bf16* __restrict__ Kl,
              bf16* __restrict__ Vt) {
  __shared__ __align__(16) bf16 Ah[64][72], Al[64][72];  // +8 pad
  __shared__ __align__(16) bf16 Bh[64][72], Bl[64][72];
  const int tid  = threadIdx.x;
  const int lane = tid & 63, wave = tid >> 6;
  const int m0 = blockIdx.x * 64, n0 = blockIdx.y * 64;
  const int wm = (wave >> 1) * 32, wn = (wave & 1) * 32;
  const int c = lane & 15, quad = lane >> 4;
  const int fr = tid >> 4, fc = (tid & 15) * 4;  // fp32 staging

  const f32x4 zero = {0.f, 0.f, 0.f, 0.f};
  f32x4 acc[2][2];
  acc[0][0] = zero; acc[0][1] = zero; acc[1][0] = zero; acc[1][1] = zero;

  for (int k0 = 0; k0 < 512; k0 += 64) {
#pragma unroll
    for (int rr = 0; rr < 4; ++rr) {
      const int row = rr * 16 + fr;
      f32x4 av = *(const f32x4*)&A [(size_t)(m0 + row) * 512 + k0 + fc];
      f32x4 bv = *(const f32x4*)&Bm[(size_t)(n0 + row) * 512 + k0 + fc];
      bf16x4 ah, al, bh, bl;
#pragma unroll
      for (int j = 0; j < 4; ++j) {
        bf16 h = (bf16)av[j]; ah[j] = h; al[j] = (bf16)(av[j] - (float)h);
        bf16 g = (bf16)bv[j]; bh[j] = g; bl[j] = (bf16)(bv[j] - (float)g);
      }
      *(bf16x4*)&Ah[row][fc] = ah; *(bf16x4*)&Al[row][fc] = al;
      *(bf16x4*)&Bh[row][fc] = bh; *(bf16x4*)&Bl[row][fc] = bl;
    }
    __syncthreads();
#pragma unroll
    for (int ks = 0; ks < 64; ks += 32) {
      bf16x8 ah0 = *(bf16x8*)&Ah[wm + c     ][ks + quad * 8];
      bf16x8 ah1 = *(bf16x8*)&Ah[wm + 16 + c][ks + quad * 8];
      bf16x8 al0 = *(bf16x8*)&Al[wm + c     ][ks + quad * 8];
      bf16x8 al1 = *(bf16x8*)&Al[wm + 16 + c][ks + quad * 8];
      bf16x8 bh0 = *(bf16x8*)&Bh[wn + c     ][ks + quad * 8];
      bf16x8 bh1 = *(bf16x8*)&Bh[wn + 16 + c][ks + quad * 8];
      bf16x8 bl0 = *(bf16x8*)&Bl[wn + c     ][ks + quad * 8];
      bf16x8 bl1 = *(bf16x8*)&Bl[wn + 16 + c][ks + quad * 8];
      acc[0][0] = MFMA(ah0, bh0, acc[0][0]);
      acc[0][0] = MFMA(al0, bh0, acc[0][0]);
      acc[0][0] = MFMA(ah0, bl0, acc[0][0]);
      acc[0][1] = MFMA(ah0, bh1, acc[0][1]);
      acc[0][1] = MFMA(al0, bh1, acc[0][1]);
      acc[0][1] = MFMA(ah0, bl1, acc[0][1]);
      acc[1][0] = MFMA(ah1, bh0, acc[1][0]);
      acc[1][0] = MFMA(al1, bh0, acc[1][0]);
      acc[1][0] = MFMA(ah1, bl0, acc[1][0]);
      acc[1][1] = MFMA(ah1, bh1, acc[1][1]);
      acc[1][1] = MFMA(al1, bh1, acc[1][1]);
      acc[1][1] = MFMA(ah1, bl1, acc[1][1]);
    }
    __syncthreads();
  }

  // epilogue: C/D layout row = quad*4+r, col = c (m89-verified)
#pragma unroll
  for (int mt = 0; mt < 2; ++mt) {
#pragma unroll
    for (int nt = 0; nt < 2; ++nt) {
      const int n = n0 + wn + nt * 16 + c;
      const float bv = bias[n];
#pragma unroll
      for (int r = 0; r < 4; ++r) {
        const int m = m0 + wm + mt * 16 + quad * 4 + r;
        float v = acc[mt][nt][r] + bv;
        const int h = n / 192, t = n % 192;
        const size_t bh = (size_t)((m >> 11) * 8 + h);  // b*8 + h
        const int s = m & 2047;
        if (t < 64) {                      // Q: fold in sqrt(512), hi/lo split
          float q = v * SCALE;
          bf16 hi = (bf16)q;
          float lo = q - (float)hi;
          size_t idx = (bh * SEQ + s) * HD + t;
          Qh[idx] = hi; Ql[idx] = (bf16)lo;
        } else if (t < 128) {              // K: hi/lo split
          bf16 hi = (bf16)v;
          float lo = v - (float)hi;
          size_t idx = (bh * SEQ + s) * HD + (t - 64);
          Kh[idx] = hi; Kl[idx] = (bf16)lo;
        } else {                           // V: transposed [bh][d][s]
          Vt[(bh * HD + (t - 128)) * SEQ + s] = (bf16)v;
        }
      }
    }
  }
}

// ---------------------------------------------------------------------------
// Output projection: out[M,512] = O[M,512] @ Wout[512,512]^T + b.
// OUTPUT IS FP32 (reference returns float32; no bf16 anywhere in the harness).
// ---------------------------------------------------------------------------
__global__ __launch_bounds__(256)
void gemm_out(const bf16* __restrict__ A, const float* __restrict__ Bm,
              const float* __restrict__ bias, float* __restrict__ C) {
  __shared__ __align__(16) bf16 As[64][72];
  __shared__ __align__(16) bf16 Bs[64][72];
  const int tid  = threadIdx.x;
  const int lane = tid & 63, wave = tid >> 6;
  const int m0 = blockIdx.x * 64, n0 = blockIdx.y * 64;
  const int wm = (wave >> 1) * 32, wn = (wave & 1) * 32;
  const int c = lane & 15, quad = lane >> 4;
  const int lr = tid >> 3, lc = (tid & 7) * 8;
  const int fr = tid >> 4, fc = (tid & 15) * 4;

  const f32x4 zero = {0.f, 0.f, 0.f, 0.f};
  f32x4 acc[2][2];
  acc[0][0] = zero; acc[0][1] = zero; acc[1][0] = zero; acc[1][1] = zero;

  for (int k0 = 0; k0 < 512; k0 += 64) {
    *(bf16x8*)&As[lr][lc]      = *(const bf16x8*)&A[(size_t)(m0 + lr     ) * 512 + k0 + lc];
    *(bf16x8*)&As[lr + 32][lc] = *(const bf16x8*)&A[(size_t)(m0 + lr + 32) * 512 + k0 + lc];
#pragma unroll
    for (int rr = 0; rr < 4; ++rr) {
      const int row = rr * 16 + fr;
      f32x4 bv = *(const f32x4*)&Bm[(size_t)(n0 + row) * 512 + k0 + fc];
      bf16x4 bb;
#pragma unroll
      for (int j = 0; j < 4; ++j) bb[j] = (bf16)bv[j];
      *(bf16x4*)&Bs[row][fc] = bb;
    }
    __syncthreads();
#pragma unroll
    for (int ks = 0; ks < 64; ks += 32) {
      bf16x8 a0 = *(bf16x8*)&As[wm + c     ][ks + quad * 8];
      bf16x8 a1 = *(bf16x8*)&As[wm + 16 + c][ks + quad * 8];
      bf16x8 b0 = *(bf16x8*)&Bs[wn + c     ][ks + quad * 8];
      bf16x8 b1 = *(bf16x8*)&Bs[wn + 16 + c][ks + quad * 8];
      acc[0][0] = MFMA(a0, b0, acc[0][0]);
      acc[0][1] = MFMA(a0, b1, acc[0][1]);
      acc[1][0] = MFMA(a1, b0, acc[1][0]);
      acc[1][1] = MFMA(a1, b1, acc[1][1]);
    }
    __syncthreads();
  }

#pragma unroll
  for (int mt = 0; mt < 2; ++mt) {
#pragma unroll
    for (int nt = 0; nt < 2; ++nt) {
      const int n = n0 + wn + nt * 16 + c;
      const float bv = bias[n];
#pragma unroll
      for (int r = 0; r < 4; ++r) {
        const int m = m0 + wm + mt * 16 + quad * 4 + r;
        C[(size_t)m * 512 + n] = acc[mt][nt][r] + bv;   // fp32 store
      }
    }
  }
}

// ---------------------------------------------------------------------------
// Attention with double softmax (MFMA). grid (SEQ/64, 32 heads), block 256.
// Each wave owns 16 queries. pass1: online (m, L1); pass2: t = exp(exp(s-m)/L1),
// o += t*V, L2 += t. Second softmax needs no max: attn1 in [0,1] -> t in [1,e].
// Validated R3/R4: bit-identical output vs correct-by-construction VALU version.
// ---------------------------------------------------------------------------
__global__ __launch_bounds__(256)
void attn_kernel(const bf16* __restrict__ Qh, const bf16* __restrict__ Ql,
                 const bf16* __restrict__ Kh, const bf16* __restrict__ Kl,
                 const bf16* __restrict__ Vt, bf16* __restrict__ O) {
  __shared__ __align__(16) bf16 tls[4][16][72];  // per-wave t-tile, C->A layout
  const int lane = threadIdx.x & 63, wave = threadIdx.x >> 6;
  const int c = lane & 15, quad = lane >> 4;
  const int bh = blockIdx.y;
  const int q0 = blockIdx.x * 64 + wave * 16;
  const size_t hoff = (size_t)bh * SEQ * HD;
  const bf16* qh_p = Qh + hoff;
  const bf16* ql_p = Ql + hoff;
  const bf16* kh_p = Kh + hoff;
  const bf16* kl_p = Kl + hoff;
  const bf16* vt_p = Vt + hoff;    // [HD][SEQ] per head
  const f32x4 zero = {0.f, 0.f, 0.f, 0.f};

  // Q fragments (A-operand: m = lane&15, k = quad*8+j), hi+lo
  bf16x8 qh[2], ql[2];
#pragma unroll
  for (int t = 0; t < 2; ++t) {
    size_t off = (size_t)(q0 + c) * HD + t * 32 + quad * 8;
    qh[t] = *(const bf16x8*)&qh_p[off];
    ql[t] = *(const bf16x8*)&ql_p[off];
  }

  float mr[4] = {NEG_SEED, NEG_SEED, NEG_SEED, NEG_SEED};
  float l1[4] = {0.f, 0.f, 0.f, 0.f};

  // ---- pass 1: per-lane online max/sum over this lane's key columns ----
  for (int kc = 0; kc < SEQ; kc += 64) {
#pragma unroll
    for (int kt = 0; kt < 4; ++kt) {
      f32x4 sc = zero;
#pragma unroll
      for (int t = 0; t < 2; ++t) {
        size_t off = (size_t)(kc + kt * 16 + c) * HD + t * 32 + quad * 8;
        bf16x8 kh = *(const bf16x8*)&kh_p[off];
        bf16x8 kl = *(const bf16x8*)&kl_p[off];
        sc = MFMA(qh[t], kh, sc);
        sc = MFMA(ql[t], kh, sc);
        sc = MFMA(qh[t], kl, sc);
      }
#pragma unroll
      for (int r = 0; r < 4; ++r) {
        float v = sc[r];
        float nm = fmaxf(mr[r], v);
        l1[r] = l1[r] * __expf(mr[r] - nm) + __expf(v - nm);
        mr[r] = nm;
      }
    }
  }
  // merge (m, L1) across the 16 lanes holding each row (xor 1,2,4,8: stays in quad)
#pragma unroll
  for (int r = 0; r < 4; ++r) {
#pragma unroll
    for (int off = 1; off < 16; off <<= 1) {
      float mo = __shfl_xor(mr[r], off, 64);
      float lo = __shfl_xor(l1[r], off, 64);
      float nm = fmaxf(mr[r], mo);
      l1[r] = l1[r] * __expf(mr[r] - nm) + lo * __expf(mo - nm);
      mr[r] = nm;
    }
  }
  float inv1[4];
#pragma unroll
  for (int r = 0; r < 4; ++r) inv1[r] = 1.f / l1[r];

  f32x4 oacc[4]; oacc[0] = zero; oacc[1] = zero; oacc[2] = zero; oacc[3] = zero;
  float l2[4] = {0.f, 0.f, 0.f, 0.f};

  // ---- pass 2: recompute s, t = exp(attn1), accumulate t*V and L2 ----
  for (int kc = 0; kc < SEQ; kc += 64) {
#pragma unroll
    for (int kt = 0; kt < 4; ++kt) {
      f32x4 sc = zero;
#pragma unroll
      for (int t = 0; t < 2; ++t) {
        size_t off = (size_t)(kc + kt * 16 + c) * HD + t * 32 + quad * 8;
        bf16x8 kh = *(const bf16x8*)&kh_p[off];
        bf16x8 kl = *(const bf16x8*)&kl_p[off];
        sc = MFMA(qh[t], kh, sc);
        sc = MFMA(ql[t], kh, sc);
        sc = MFMA(qh[t], kl, sc);
      }
#pragma unroll
      for (int r = 0; r < 4; ++r) {
        float a1 = __expf(sc[r] - mr[r]) * inv1[r];  // attn1 in [0,1]
        float tv = __expf(a1);                       // t in [1,e]
        l2[r] += tv;
        tls[wave][quad * 4 + r][kt * 16 + c] = (bf16)tv;
      }
    }
    __syncthreads();
#pragma unroll
    for (int t = 0; t < 2; ++t) {
      bf16x8 ta = *(bf16x8*)&tls[wave][c][t * 32 + quad * 8];  // A-frag of t
#pragma unroll
      for (int dt = 0; dt < 4; ++dt) {
        bf16x8 vb = *(const bf16x8*)&vt_p[(size_t)(dt * 16 + c) * SEQ + kc + t * 32 + quad * 8];
        oacc[dt] = MFMA(ta, vb, oacc[dt]);
      }
    }
    __syncthreads();
  }

  // reduce L2 across the 16 lanes per row
#pragma unroll
  for (int r = 0; r < 4; ++r) {
#pragma unroll
    for (int off = 1; off < 16; off <<= 1) l2[r] += __shfl_xor(l2[r], off, 64);
  }

  // write O[b, s, h*64 + d] (bf16 scratch)
  const int b = bh >> 3, h = bh & 7;
#pragma unroll
  for (int dt = 0; dt < 4; ++dt) {
#pragma unroll
    for (int r = 0; r < 4; ++r) {
      const int srow = q0 + quad * 4 + r;
      const int e = h * HD + dt * 16 + c;
      O[((size_t)b * SEQ + srow) * EMB + e] = (bf16)(oacc[dt][r] / l2[r]);
    }
  }
}

// ---------------------------------------------------------------------------
extern "C" void kernel_launch(void* const* d_in, const int* in_sizes, int n_in,
                              void* d_out, int out_size, void* d_ws, size_t ws_size,
                              hipStream_t stream) {
  const float* x    = (const float*)d_in[0];  // [4,2048,512] fp32
  const float* Wqkv = (const float*)d_in[1];  // [1536,512]  fp32
  const float* bqkv = (const float*)d_in[2];  // [1536]      fp32
  const float* Wout = (const float*)d_in[3];  // [512,512]   fp32
  const float* bout = (const float*)d_in[4];  // [512]       fp32
  float* out = (float*)d_out;                 // [4,2048,512] fp32

  char* ws = (char*)d_ws;
  const size_t SZ = (size_t)32 * SEQ * HD * 2;  // 8 MB per array (48 MB total)
  bf16* Qh = (bf16*)(ws + 0 * SZ);
  bf16* Ql = (bf16*)(ws + 1 * SZ);
  bf16* Kh = (bf16*)(ws + 2 * SZ);
  bf16* Kl = (bf16*)(ws + 3 * SZ);
  bf16* Vt = (bf16*)(ws + 4 * SZ);
  bf16* O  = (bf16*)(ws + 5 * SZ);

  gemm_qkv<<<dim3(128, 24), 256, 0, stream>>>(x, Wqkv, bqkv, Qh, Ql, Kh, Kl, Vt);
  attn_kernel<<<dim3(SEQ / 64, 32), 256, 0, stream>>>(Qh, Ql, Kh, Kl, Vt, O);
  gemm_out<<<dim3(128, 8), 256, 0, stream>>>(O, Wout, bout, out);
}

// Round 6
// 345.886 us; speedup vs baseline: 2.5217x; 2.5217x over previous
//
#include <hip/hip_runtime.h>

typedef __bf16 bf16;
typedef __attribute__((ext_vector_type(4))) __bf16 bf16x4;
typedef __attribute__((ext_vector_type(8))) __bf16 bf16x8;
typedef __attribute__((ext_vector_type(4))) float f32x4;

#define MFMA(A,B,C) __builtin_amdgcn_mfma_f32_16x16x32_bf16(A,B,C,0,0,0)

#define SEQ 2048
#define EMB 512
#define HD  64
#define SCALE 22.627416997969522f  // sqrt(512): scores are divided by E^-0.5
// Online-softmax seed: not -inf (fast-math folds inf constants to poison).
#define NEG_SEED -3.0e4f

// ---------------------------------------------------------------------------
// QKV projection: C[M,N] = x[M,512] @ W[N,512]^T + b[n], fp32 in.
// Both operands hi/lo-split at LDS staging; 3 MFMAs give ~17-bit precision.
// Epilogue: Qh/Ql (pre-scaled), Kh/Kl [bh][s][d], V^T [bh][d][s].
// ---------------------------------------------------------------------------
__global__ __launch_bounds__(256)
void gemm_qkv(const float* __restrict__ A, const float* __restrict__ Bm,
              const float* __restrict__ bias,
              bf16* __restrict__ Qh, bf16* __restrict__ Ql,
              bf16* __restrict__ Kh, bf16* __restrict__ Kl,
              bf16* __restrict__ Vt) {
  __shared__ __align__(16) bf16 Ah[64][72], Al[64][72];
  __shared__ __align__(16) bf16 Bh[64][72], Bl[64][72];
  const int tid  = threadIdx.x;
  const int lane = tid & 63, wave = tid >> 6;
  const int m0 = blockIdx.x * 64, n0 = blockIdx.y * 64;
  const int wm = (wave >> 1) * 32, wn = (wave & 1) * 32;
  const int c = lane & 15, quad = lane >> 4;
  const int fr = tid >> 4, fc = (tid & 15) * 4;

  const f32x4 zero = {0.f, 0.f, 0.f, 0.f};
  f32x4 acc[2][2];
  acc[0][0] = zero; acc[0][1] = zero; acc[1][0] = zero; acc[1][1] = zero;

  for (int k0 = 0; k0 < 512; k0 += 64) {
#pragma unroll
    for (int rr = 0; rr < 4; ++rr) {
      const int row = rr * 16 + fr;
      f32x4 av = *(const f32x4*)&A [(size_t)(m0 + row) * 512 + k0 + fc];
      f32x4 bv = *(const f32x4*)&Bm[(size_t)(n0 + row) * 512 + k0 + fc];
      bf16x4 ah, al, bh, bl;
#pragma unroll
      for (int j = 0; j < 4; ++j) {
        bf16 h = (bf16)av[j]; ah[j] = h; al[j] = (bf16)(av[j] - (float)h);
        bf16 g = (bf16)bv[j]; bh[j] = g; bl[j] = (bf16)(bv[j] - (float)g);
      }
      *(bf16x4*)&Ah[row][fc] = ah; *(bf16x4*)&Al[row][fc] = al;
      *(bf16x4*)&Bh[row][fc] = bh; *(bf16x4*)&Bl[row][fc] = bl;
    }
    __syncthreads();
#pragma unroll
    for (int ks = 0; ks < 64; ks += 32) {
      bf16x8 ah0 = *(bf16x8*)&Ah[wm + c     ][ks + quad * 8];
      bf16x8 ah1 = *(bf16x8*)&Ah[wm + 16 + c][ks + quad * 8];
      bf16x8 al0 = *(bf16x8*)&Al[wm + c     ][ks + quad * 8];
      bf16x8 al1 = *(bf16x8*)&Al[wm + 16 + c][ks + quad * 8];
      bf16x8 bh0 = *(bf16x8*)&Bh[wn + c     ][ks + quad * 8];
      bf16x8 bh1 = *(bf16x8*)&Bh[wn + 16 + c][ks + quad * 8];
      bf16x8 bl0 = *(bf16x8*)&Bl[wn + c     ][ks + quad * 8];
      bf16x8 bl1 = *(bf16x8*)&Bl[wn + 16 + c][ks + quad * 8];
      acc[0][0] = MFMA(ah0, bh0, acc[0][0]);
      acc[0][0] = MFMA(al0, bh0, acc[0][0]);
      acc[0][0] = MFMA(ah0, bl0, acc[0][0]);
      acc[0][1] = MFMA(ah0, bh1, acc[0][1]);
      acc[0][1] = MFMA(al0, bh1, acc[0][1]);
      acc[0][1] = MFMA(ah0, bl1, acc[0][1]);
      acc[1][0] = MFMA(ah1, bh0, acc[1][0]);
      acc[1][0] = MFMA(al1, bh0, acc[1][0]);
      acc[1][0] = MFMA(ah1, bl0, acc[1][0]);
      acc[1][1] = MFMA(ah1, bh1, acc[1][1]);
      acc[1][1] = MFMA(al1, bh1, acc[1][1]);
      acc[1][1] = MFMA(ah1, bl1, acc[1][1]);
    }
    __syncthreads();
  }

#pragma unroll
  for (int mt = 0; mt < 2; ++mt) {
#pragma unroll
    for (int nt = 0; nt < 2; ++nt) {
      const int n = n0 + wn + nt * 16 + c;
      const float bv = bias[n];
#pragma unroll
      for (int r = 0; r < 4; ++r) {
        const int m = m0 + wm + mt * 16 + quad * 4 + r;
        float v = acc[mt][nt][r] + bv;
        const int h = n / 192, t = n % 192;
        const size_t bh = (size_t)((m >> 11) * 8 + h);
        const int s = m & 2047;
        if (t < 64) {
          float q = v * SCALE;
          bf16 hi = (bf16)q;
          float lo = q - (float)hi;
          size_t idx = (bh * SEQ + s) * HD + t;
          Qh[idx] = hi; Ql[idx] = (bf16)lo;
        } else if (t < 128) {
          bf16 hi = (bf16)v;
          float lo = v - (float)hi;
          size_t idx = (bh * SEQ + s) * HD + (t - 64);
          Kh[idx] = hi; Kl[idx] = (bf16)lo;
        } else {
          Vt[(bh * HD + (t - 128)) * SEQ + s] = (bf16)v;
        }
      }
    }
  }
}

// ---------------------------------------------------------------------------
// Output projection: out[M,512] = O[M,512] @ Wout[512,512]^T + b. FP32 OUT.
// ---------------------------------------------------------------------------
__global__ __launch_bounds__(256)
void gemm_out(const bf16* __restrict__ A, const float* __restrict__ Bm,
              const float* __restrict__ bias, float* __restrict__ C) {
  __shared__ __align__(16) bf16 As[64][72];
  __shared__ __align__(16) bf16 Bs[64][72];
  const int tid  = threadIdx.x;
  const int lane = tid & 63, wave = tid >> 6;
  const int m0 = blockIdx.x * 64, n0 = blockIdx.y * 64;
  const int wm = (wave >> 1) * 32, wn = (wave & 1) * 32;
  const int c = lane & 15, quad = lane >> 4;
  const int lr = tid >> 3, lc = (tid & 7) * 8;
  const int fr = tid >> 4, fc = (tid & 15) * 4;

  const f32x4 zero = {0.f, 0.f, 0.f, 0.f};
  f32x4 acc[2][2];
  acc[0][0] = zero; acc[0][1] = zero; acc[1][0] = zero; acc[1][1] = zero;

  for (int k0 = 0; k0 < 512; k0 += 64) {
    *(bf16x8*)&As[lr][lc]      = *(const bf16x8*)&A[(size_t)(m0 + lr     ) * 512 + k0 + lc];
    *(bf16x8*)&As[lr + 32][lc] = *(const bf16x8*)&A[(size_t)(m0 + lr + 32) * 512 + k0 + lc];
#pragma unroll
    for (int rr = 0; rr < 4; ++rr) {
      const int row = rr * 16 + fr;
      f32x4 bv = *(const f32x4*)&Bm[(size_t)(n0 + row) * 512 + k0 + fc];
      bf16x4 bb;
#pragma unroll
      for (int j = 0; j < 4; ++j) bb[j] = (bf16)bv[j];
      *(bf16x4*)&Bs[row][fc] = bb;
    }
    __syncthreads();
#pragma unroll
    for (int ks = 0; ks < 64; ks += 32) {
      bf16x8 a0 = *(bf16x8*)&As[wm + c     ][ks + quad * 8];
      bf16x8 a1 = *(bf16x8*)&As[wm + 16 + c][ks + quad * 8];
      bf16x8 b0 = *(bf16x8*)&Bs[wn + c     ][ks + quad * 8];
      bf16x8 b1 = *(bf16x8*)&Bs[wn + 16 + c][ks + quad * 8];
      acc[0][0] = MFMA(a0, b0, acc[0][0]);
      acc[0][1] = MFMA(a0, b1, acc[0][1]);
      acc[1][0] = MFMA(a1, b0, acc[1][0]);
      acc[1][1] = MFMA(a1, b1, acc[1][1]);
    }
    __syncthreads();
  }

#pragma unroll
  for (int mt = 0; mt < 2; ++mt) {
#pragma unroll
    for (int nt = 0; nt < 2; ++nt) {
      const int n = n0 + wn + nt * 16 + c;
      const float bv = bias[n];
#pragma unroll
      for (int r = 0; r < 4; ++r) {
        const int m = m0 + wm + mt * 16 + quad * 4 + r;
        C[(size_t)m * 512 + n] = acc[mt][nt][r] + bv;
      }
    }
  }
}

// ---------------------------------------------------------------------------
// Attention, double softmax. grid (32 bh, SEQ/64), block 256.
// blockIdx.x = bh so all q-chunks of one head land on one XCD (i%8 round
// robin on linear block id) -> K/V stay L2-resident.
// K (and V in pass 2) staged in block-shared LDS, double-buffered: global
// loads for chunk i+1 issue before compute of chunk i; regs->padded LDS;
// ONE barrier per chunk. t-tile LDS round-trip is per-wave (DS ops are
// wave-ordered) -> no barrier needed for it.
// ---------------------------------------------------------------------------
__global__ __launch_bounds__(256)
void attn_kernel(const bf16* __restrict__ Qh, const bf16* __restrict__ Ql,
                 const bf16* __restrict__ Kh, const bf16* __restrict__ Kl,
                 const bf16* __restrict__ Vt, bf16* __restrict__ O) {
  __shared__ __align__(16) bf16 KhS[2][64][72];   // 18432 B
  __shared__ __align__(16) bf16 KlS[2][64][72];   // 18432 B
  __shared__ __align__(16) bf16 VtS[2][64][72];   // 18432 B
  __shared__ __align__(16) bf16 tls[4][16][72];   //  9216 B   (total 64512)
  const int tid  = threadIdx.x;
  const int lane = tid & 63, wave = tid >> 6;
  const int c = lane & 15, quad = lane >> 4;
  const int bh = blockIdx.x;                       // XCD swizzle
  const int q0 = blockIdx.y * 64 + wave * 16;
  const size_t hoff = (size_t)bh * SEQ * HD;
  const bf16* qh_p = Qh + hoff;
  const bf16* ql_p = Ql + hoff;
  const bf16* kh_p = Kh + hoff;
  const bf16* kl_p = Kl + hoff;
  const bf16* vt_p = Vt + hoff;                    // [HD][SEQ]
  const f32x4 zero = {0.f, 0.f, 0.f, 0.f};

  const int sr  = tid >> 3;        // staging row 0..31
  const int sc8 = (tid & 7) * 8;   // staging col (8 bf16 = 16 B)

  // Q fragments (A-operand: m = lane&15, k = quad*8+j), hi+lo
  bf16x8 qh[2], ql[2];
#pragma unroll
  for (int t = 0; t < 2; ++t) {
    size_t off = (size_t)(q0 + c) * HD + t * 32 + quad * 8;
    qh[t] = *(const bf16x8*)&qh_p[off];
    ql[t] = *(const bf16x8*)&ql_p[off];
  }

  float mr[4] = {NEG_SEED, NEG_SEED, NEG_SEED, NEG_SEED};
  float l1[4] = {0.f, 0.f, 0.f, 0.f};

  // ================= pass 1: online (m, L1) =================
  bf16x8 p0, p1, p2, p3;
  p0 = *(const bf16x8*)&kh_p[(size_t)(sr     ) * HD + sc8];
  p1 = *(const bf16x8*)&kh_p[(size_t)(sr + 32) * HD + sc8];
  p2 = *(const bf16x8*)&kl_p[(size_t)(sr     ) * HD + sc8];
  p3 = *(const bf16x8*)&kl_p[(size_t)(sr + 32) * HD + sc8];
  *(bf16x8*)&KhS[0][sr     ][sc8] = p0;
  *(bf16x8*)&KhS[0][sr + 32][sc8] = p1;
  *(bf16x8*)&KlS[0][sr     ][sc8] = p2;
  *(bf16x8*)&KlS[0][sr + 32][sc8] = p3;
  __syncthreads();
  int buf = 0;
  for (int ch = 0; ch < 32; ++ch) {
    if (ch < 31) {
      const size_t k0 = (size_t)(ch + 1) * 64;
      p0 = *(const bf16x8*)&kh_p[(k0 + sr     ) * HD + sc8];
      p1 = *(const bf16x8*)&kh_p[(k0 + sr + 32) * HD + sc8];
      p2 = *(const bf16x8*)&kl_p[(k0 + sr     ) * HD + sc8];
      p3 = *(const bf16x8*)&kl_p[(k0 + sr + 32) * HD + sc8];
    }
#pragma unroll
    for (int kt = 0; kt < 4; ++kt) {
      f32x4 sc = zero;
#pragma unroll
      for (int t = 0; t < 2; ++t) {
        bf16x8 khf = *(bf16x8*)&KhS[buf][kt * 16 + c][t * 32 + quad * 8];
        bf16x8 klf = *(bf16x8*)&KlS[buf][kt * 16 + c][t * 32 + quad * 8];
        sc = MFMA(qh[t], khf, sc);
        sc = MFMA(ql[t], khf, sc);
        sc = MFMA(qh[t], klf, sc);
      }
#pragma unroll
      for (int r = 0; r < 4; ++r) {
        float v = sc[r];
        float nm = fmaxf(mr[r], v);
        l1[r] = l1[r] * __expf(mr[r] - nm) + __expf(v - nm);
        mr[r] = nm;
      }
    }
    if (ch < 31) {
      *(bf16x8*)&KhS[buf ^ 1][sr     ][sc8] = p0;
      *(bf16x8*)&KhS[buf ^ 1][sr + 32][sc8] = p1;
      *(bf16x8*)&KlS[buf ^ 1][sr     ][sc8] = p2;
      *(bf16x8*)&KlS[buf ^ 1][sr + 32][sc8] = p3;
      __syncthreads();
      buf ^= 1;
    }
  }
  // merge (m, L1) across the 16 lanes holding each row
#pragma unroll
  for (int r = 0; r < 4; ++r) {
#pragma unroll
    for (int off = 1; off < 16; off <<= 1) {
      float mo = __shfl_xor(mr[r], off, 64);
      float lo = __shfl_xor(l1[r], off, 64);
      float nm = fmaxf(mr[r], mo);
      l1[r] = l1[r] * __expf(mr[r] - nm) + lo * __expf(mo - nm);
      mr[r] = nm;
    }
  }
  float inv1[4];
#pragma unroll
  for (int r = 0; r < 4; ++r) inv1[r] = 1.f / l1[r];

  f32x4 oacc[4]; oacc[0] = zero; oacc[1] = zero; oacc[2] = zero; oacc[3] = zero;
  float l2[4] = {0.f, 0.f, 0.f, 0.f};

  // ================= pass 2: t = exp(attn1), o += t*V =================
  bf16x8 v0, v1;
  p0 = *(const bf16x8*)&kh_p[(size_t)(sr     ) * HD + sc8];
  p1 = *(const bf16x8*)&kh_p[(size_t)(sr + 32) * HD + sc8];
  p2 = *(const bf16x8*)&kl_p[(size_t)(sr     ) * HD + sc8];
  p3 = *(const bf16x8*)&kl_p[(size_t)(sr + 32) * HD + sc8];
  v0 = *(const bf16x8*)&vt_p[(size_t)(sr     ) * SEQ + sc8];
  v1 = *(const bf16x8*)&vt_p[(size_t)(sr + 32) * SEQ + sc8];
  *(bf16x8*)&KhS[0][sr     ][sc8] = p0;
  *(bf16x8*)&KhS[0][sr + 32][sc8] = p1;
  *(bf16x8*)&KlS[0][sr     ][sc8] = p2;
  *(bf16x8*)&KlS[0][sr + 32][sc8] = p3;
  *(bf16x8*)&VtS[0][sr     ][sc8] = v0;
  *(bf16x8*)&VtS[0][sr + 32][sc8] = v1;
  __syncthreads();
  buf = 0;
  for (int ch = 0; ch < 32; ++ch) {
    if (ch < 31) {
      const int k0 = (ch + 1) * 64;
      p0 = *(const bf16x8*)&kh_p[(size_t)(k0 + sr     ) * HD + sc8];
      p1 = *(const bf16x8*)&kh_p[(size_t)(k0 + sr + 32) * HD + sc8];
      p2 = *(const bf16x8*)&kl_p[(size_t)(k0 + sr     ) * HD + sc8];
      p3 = *(const bf16x8*)&kl_p[(size_t)(k0 + sr + 32) * HD + sc8];
      v0 = *(const bf16x8*)&vt_p[(size_t)(sr     ) * SEQ + k0 + sc8];
      v1 = *(const bf16x8*)&vt_p[(size_t)(sr + 32) * SEQ + k0 + sc8];
    }
#pragma unroll
    for (int kt = 0; kt < 4; ++kt) {
      f32x4 sc = zero;
#pragma unroll
      for (int t = 0; t < 2; ++t) {
        bf16x8 khf = *(bf16x8*)&KhS[buf][kt * 16 + c][t * 32 + quad * 8];
        bf16x8 klf = *(bf16x8*)&KlS[buf][kt * 16 + c][t * 32 + quad * 8];
        sc = MFMA(qh[t], khf, sc);
        sc = MFMA(ql[t], khf, sc);
        sc = MFMA(qh[t], klf, sc);
      }
#pragma unroll
      for (int r = 0; r < 4; ++r) {
        float a1 = __expf(sc[r] - mr[r]) * inv1[r];  // attn1 in [0,1]
        float tv = __expf(a1);                       // t in [1,e]
        l2[r] += tv;
        tls[wave][quad * 4 + r][kt * 16 + c] = (bf16)tv;
      }
    }
    // per-wave LDS round-trip (DS ops are wave-ordered; no barrier needed)
#pragma unroll
    for (int t = 0; t < 2; ++t) {
      bf16x8 ta = *(bf16x8*)&tls[wave][c][t * 32 + quad * 8];
#pragma unroll
      for (int dt = 0; dt < 4; ++dt) {
        bf16x8 vb = *(bf16x8*)&VtS[buf][dt * 16 + c][t * 32 + quad * 8];
        oacc[dt] = MFMA(ta, vb, oacc[dt]);
      }
    }
    if (ch < 31) {
      *(bf16x8*)&KhS[buf ^ 1][sr     ][sc8] = p0;
      *(bf16x8*)&KhS[buf ^ 1][sr + 32][sc8] = p1;
      *(bf16x8*)&KlS[buf ^ 1][sr     ][sc8] = p2;
      *(bf16x8*)&KlS[buf ^ 1][sr + 32][sc8] = p3;
      *(bf16x8*)&VtS[buf ^ 1][sr     ][sc8] = v0;
      *(bf16x8*)&VtS[buf ^ 1][sr + 32][sc8] = v1;
      __syncthreads();
      buf ^= 1;
    }
  }

  // reduce L2 across the 16 lanes per row
#pragma unroll
  for (int r = 0; r < 4; ++r) {
#pragma unroll
    for (int off = 1; off < 16; off <<= 1) l2[r] += __shfl_xor(l2[r], off, 64);
  }

  // write O[b, s, h*64 + d] (bf16 scratch)
  const int b = bh >> 3, h = bh & 7;
#pragma unroll
  for (int dt = 0; dt < 4; ++dt) {
#pragma unroll
    for (int r = 0; r < 4; ++r) {
      const int srow = q0 + quad * 4 + r;
      const int e = h * HD + dt * 16 + c;
      O[((size_t)b * SEQ + srow) * EMB + e] = (bf16)(oacc[dt][r] / l2[r]);
    }
  }
}

// ---------------------------------------------------------------------------
extern "C" void kernel_launch(void* const* d_in, const int* in_sizes, int n_in,
                              void* d_out, int out_size, void* d_ws, size_t ws_size,
                              hipStream_t stream) {
  const float* x    = (const float*)d_in[0];
  const float* Wqkv = (const float*)d_in[1];
  const float* bqkv = (const float*)d_in[2];
  const float* Wout = (const float*)d_in[3];
  const float* bout = (const float*)d_in[4];
  float* out = (float*)d_out;

  char* ws = (char*)d_ws;
  const size_t SZ = (size_t)32 * SEQ * HD * 2;  // 8 MB per array
  bf16* Qh = (bf16*)(ws + 0 * SZ);
  bf16* Ql = (bf16*)(ws + 1 * SZ);
  bf16* Kh = (bf16*)(ws + 2 * SZ);
  bf16* Kl = (bf16*)(ws + 3 * SZ);
  bf16* Vt = (bf16*)(ws + 4 * SZ);
  bf16* O  = (bf16*)(ws + 5 * SZ);

  gemm_qkv<<<dim3(128, 24), 256, 0, stream>>>(x, Wqkv, bqkv, Qh, Ql, Kh, Kl, Vt);
  attn_kernel<<<dim3(32, SEQ / 64), 256, 0, stream>>>(Qh, Ql, Kh, Kl, Vt, O);
  gemm_out<<<dim3(128, 8), 256, 0, stream>>>(O, Wout, bout, out);
}

// Round 7
// 306.148 us; speedup vs baseline: 2.8490x; 1.1298x over previous
//
#include <hip/hip_runtime.h>

typedef __bf16 bf16;
typedef __attribute__((ext_vector_type(4))) __bf16 bf16x4;
typedef __attribute__((ext_vector_type(8))) __bf16 bf16x8;
typedef __attribute__((ext_vector_type(4))) float f32x4;

#define MFMA(A,B,C) __builtin_amdgcn_mfma_f32_16x16x32_bf16(A,B,C,0,0,0)

#define SEQ 2048
#define EMB 512
#define HD  64
#define SCALE 22.627416997969522f  // sqrt(512): scores are divided by E^-0.5
// Online-softmax seed: not -inf (fast-math folds inf constants to poison).
#define NEG_SEED -3.0e4f

// ---------------------------------------------------------------------------
// QKV projection (unchanged from R6): fp32 in, hi/lo split MFMA.
// ---------------------------------------------------------------------------
__global__ __launch_bounds__(256)
void gemm_qkv(const float* __restrict__ A, const float* __restrict__ Bm,
              const float* __restrict__ bias,
              bf16* __restrict__ Qh, bf16* __restrict__ Ql,
              bf16* __restrict__ Kh, bf16* __restrict__ Kl,
              bf16* __restrict__ Vt) {
  __shared__ __align__(16) bf16 Ah[64][72], Al[64][72];
  __shared__ __align__(16) bf16 Bh[64][72], Bl[64][72];
  const int tid  = threadIdx.x;
  const int lane = tid & 63, wave = tid >> 6;
  const int m0 = blockIdx.x * 64, n0 = blockIdx.y * 64;
  const int wm = (wave >> 1) * 32, wn = (wave & 1) * 32;
  const int c = lane & 15, quad = lane >> 4;
  const int fr = tid >> 4, fc = (tid & 15) * 4;

  const f32x4 zero = {0.f, 0.f, 0.f, 0.f};
  f32x4 acc[2][2];
  acc[0][0] = zero; acc[0][1] = zero; acc[1][0] = zero; acc[1][1] = zero;

  for (int k0 = 0; k0 < 512; k0 += 64) {
#pragma unroll
    for (int rr = 0; rr < 4; ++rr) {
      const int row = rr * 16 + fr;
      f32x4 av = *(const f32x4*)&A [(size_t)(m0 + row) * 512 + k0 + fc];
      f32x4 bv = *(const f32x4*)&Bm[(size_t)(n0 + row) * 512 + k0 + fc];
      bf16x4 ah, al, bh, bl;
#pragma unroll
      for (int j = 0; j < 4; ++j) {
        bf16 h = (bf16)av[j]; ah[j] = h; al[j] = (bf16)(av[j] - (float)h);
        bf16 g = (bf16)bv[j]; bh[j] = g; bl[j] = (bf16)(bv[j] - (float)g);
      }
      *(bf16x4*)&Ah[row][fc] = ah; *(bf16x4*)&Al[row][fc] = al;
      *(bf16x4*)&Bh[row][fc] = bh; *(bf16x4*)&Bl[row][fc] = bl;
    }
    __syncthreads();
#pragma unroll
    for (int ks = 0; ks < 64; ks += 32) {
      bf16x8 ah0 = *(bf16x8*)&Ah[wm + c     ][ks + quad * 8];
      bf16x8 ah1 = *(bf16x8*)&Ah[wm + 16 + c][ks + quad * 8];
      bf16x8 al0 = *(bf16x8*)&Al[wm + c     ][ks + quad * 8];
      bf16x8 al1 = *(bf16x8*)&Al[wm + 16 + c][ks + quad * 8];
      bf16x8 bh0 = *(bf16x8*)&Bh[wn + c     ][ks + quad * 8];
      bf16x8 bh1 = *(bf16x8*)&Bh[wn + 16 + c][ks + quad * 8];
      bf16x8 bl0 = *(bf16x8*)&Bl[wn + c     ][ks + quad * 8];
      bf16x8 bl1 = *(bf16x8*)&Bl[wn + 16 + c][ks + quad * 8];
      acc[0][0] = MFMA(ah0, bh0, acc[0][0]);
      acc[0][0] = MFMA(al0, bh0, acc[0][0]);
      acc[0][0] = MFMA(ah0, bl0, acc[0][0]);
      acc[0][1] = MFMA(ah0, bh1, acc[0][1]);
      acc[0][1] = MFMA(al0, bh1, acc[0][1]);
      acc[0][1] = MFMA(ah0, bl1, acc[0][1]);
      acc[1][0] = MFMA(ah1, bh0, acc[1][0]);
      acc[1][0] = MFMA(al1, bh0, acc[1][0]);
      acc[1][0] = MFMA(ah1, bl0, acc[1][0]);
      acc[1][1] = MFMA(ah1, bh1, acc[1][1]);
      acc[1][1] = MFMA(al1, bh1, acc[1][1]);
      acc[1][1] = MFMA(ah1, bl1, acc[1][1]);
    }
    __syncthreads();
  }

#pragma unroll
  for (int mt = 0; mt < 2; ++mt) {
#pragma unroll
    for (int nt = 0; nt < 2; ++nt) {
      const int n = n0 + wn + nt * 16 + c;
      const float bv = bias[n];
#pragma unroll
      for (int r = 0; r < 4; ++r) {
        const int m = m0 + wm + mt * 16 + quad * 4 + r;
        float v = acc[mt][nt][r] + bv;
        const int h = n / 192, t = n % 192;
        const size_t bh = (size_t)((m >> 11) * 8 + h);
        const int s = m & 2047;
        if (t < 64) {
          float q = v * SCALE;
          bf16 hi = (bf16)q;
          float lo = q - (float)hi;
          size_t idx = (bh * SEQ + s) * HD + t;
          Qh[idx] = hi; Ql[idx] = (bf16)lo;
        } else if (t < 128) {
          bf16 hi = (bf16)v;
          float lo = v - (float)hi;
          size_t idx = (bh * SEQ + s) * HD + (t - 64);
          Kh[idx] = hi; Kl[idx] = (bf16)lo;
        } else {
          Vt[(bh * HD + (t - 128)) * SEQ + s] = (bf16)v;
        }
      }
    }
  }
}

// ---------------------------------------------------------------------------
// Output projection (unchanged): fp32 out.
// ---------------------------------------------------------------------------
__global__ __launch_bounds__(256)
void gemm_out(const bf16* __restrict__ A, const float* __restrict__ Bm,
              const float* __restrict__ bias, float* __restrict__ C) {
  __shared__ __align__(16) bf16 As[64][72];
  __shared__ __align__(16) bf16 Bs[64][72];
  const int tid  = threadIdx.x;
  const int lane = tid & 63, wave = tid >> 6;
  const int m0 = blockIdx.x * 64, n0 = blockIdx.y * 64;
  const int wm = (wave >> 1) * 32, wn = (wave & 1) * 32;
  const int c = lane & 15, quad = lane >> 4;
  const int lr = tid >> 3, lc = (tid & 7) * 8;
  const int fr = tid >> 4, fc = (tid & 15) * 4;

  const f32x4 zero = {0.f, 0.f, 0.f, 0.f};
  f32x4 acc[2][2];
  acc[0][0] = zero; acc[0][1] = zero; acc[1][0] = zero; acc[1][1] = zero;

  for (int k0 = 0; k0 < 512; k0 += 64) {
    *(bf16x8*)&As[lr][lc]      = *(const bf16x8*)&A[(size_t)(m0 + lr     ) * 512 + k0 + lc];
    *(bf16x8*)&As[lr + 32][lc] = *(const bf16x8*)&A[(size_t)(m0 + lr + 32) * 512 + k0 + lc];
#pragma unroll
    for (int rr = 0; rr < 4; ++rr) {
      const int row = rr * 16 + fr;
      f32x4 bv = *(const f32x4*)&Bm[(size_t)(n0 + row) * 512 + k0 + fc];
      bf16x4 bb;
#pragma unroll
      for (int j = 0; j < 4; ++j) bb[j] = (bf16)bv[j];
      *(bf16x4*)&Bs[row][fc] = bb;
    }
    __syncthreads();
#pragma unroll
    for (int ks = 0; ks < 64; ks += 32) {
      bf16x8 a0 = *(bf16x8*)&As[wm + c     ][ks + quad * 8];
      bf16x8 a1 = *(bf16x8*)&As[wm + 16 + c][ks + quad * 8];
      bf16x8 b0 = *(bf16x8*)&Bs[wn + c     ][ks + quad * 8];
      bf16x8 b1 = *(bf16x8*)&Bs[wn + 16 + c][ks + quad * 8];
      acc[0][0] = MFMA(a0, b0, acc[0][0]);
      acc[0][1] = MFMA(a0, b1, acc[0][1]);
      acc[1][0] = MFMA(a1, b0, acc[1][0]);
      acc[1][1] = MFMA(a1, b1, acc[1][1]);
    }
    __syncthreads();
  }

#pragma unroll
  for (int mt = 0; mt < 2; ++mt) {
#pragma unroll
    for (int nt = 0; nt < 2; ++nt) {
      const int n = n0 + wn + nt * 16 + c;
      const float bv = bias[n];
#pragma unroll
      for (int r = 0; r < 4; ++r) {
        const int m = m0 + wm + mt * 16 + quad * 4 + r;
        C[(size_t)m * 512 + n] = acc[mt][nt][r] + bv;
      }
    }
  }
}

// ---------------------------------------------------------------------------
// Attention, double softmax — S^T orientation (A=K, B=Q): lane's 4 C-regs =
// 4 keys of ONE query -> vectorized online softmax, b64 t-writes, 2-step
// shuffle merges, b64 O-stores, no PV re-transpose (A=V^T, B=t).
// Chunk = 32 keys, double-buffered, XOR-swizzled LDS (29.7 KB -> 4 blocks/CU).
// grid (32 bh, 32 q-chunks), block 256.
// ---------------------------------------------------------------------------
__global__ __launch_bounds__(256, 4)
void attn_kernel(const bf16* __restrict__ Qh, const bf16* __restrict__ Ql,
                 const bf16* __restrict__ Kh, const bf16* __restrict__ Kl,
                 const bf16* __restrict__ Vt, bf16* __restrict__ O) {
  __shared__ __align__(16) bf16 KhS[2][32][64];  // [key][d], chunk^=(row&7)
  __shared__ __align__(16) bf16 KlS[2][32][64];
  __shared__ __align__(16) bf16 VtS[2][64][32];  // [d][key], chunk^=(row&3)
  __shared__ __align__(16) bf16 tls[4][16][40];  // per-wave t^T[q][key], +8 pad
  const int tid  = threadIdx.x;
  const int lane = tid & 63, wave = tid >> 6;
  const int c = lane & 15, quad = lane >> 4;
  const int bh = blockIdx.x;                     // XCD swizzle: head-major
  const int q0 = blockIdx.y * 64 + wave * 16;
  const size_t hoff = (size_t)bh * SEQ * HD;
  const bf16* qh_p = Qh + hoff;
  const bf16* ql_p = Ql + hoff;
  const bf16* kh_p = Kh + hoff;
  const bf16* kl_p = Kl + hoff;
  const bf16* vt_p = Vt + hoff;                  // [HD][SEQ]
  const f32x4 zero = {0.f, 0.f, 0.f, 0.f};

  // staging coords
  const int krow = tid >> 3;                          // key row 0..31
  const int kcol = (tid & 7) * 8;                     // logical col
  const int kphy = ((tid & 7) ^ (krow & 7)) * 8;      // swizzled col
  const int vrow = tid >> 2;                          // d row 0..63
  const int vcol = (tid & 3) * 8;
  const int vphy = ((tid & 3) ^ (vrow & 3)) * 8;
  // fragment read cols (swizzled)
  const int pc0 = ((0 + quad) ^ (c & 7)) * 8;         // K, t=0
  const int pc1 = ((4 + quad) ^ (c & 7)) * 8;         // K, t=1
  const int vpc = (quad ^ (c & 3)) * 8;               // V

  // Q B-fragments (n = lane&15 = query, k = quad*8+j), hi+lo
  bf16x8 qf[2], qlf[2];
#pragma unroll
  for (int t = 0; t < 2; ++t) {
    size_t off = (size_t)(q0 + c) * HD + t * 32 + quad * 8;
    qf[t]  = *(const bf16x8*)&qh_p[off];
    qlf[t] = *(const bf16x8*)&ql_p[off];
  }

  float mr = NEG_SEED, l1 = 0.f;

  // ================= pass 1: online (m, L1) =================
  bf16x8 ph, pl, pv;
  ph = *(const bf16x8*)&kh_p[(size_t)krow * HD + kcol];
  pl = *(const bf16x8*)&kl_p[(size_t)krow * HD + kcol];
  *(bf16x8*)&KhS[0][krow][kphy] = ph;
  *(bf16x8*)&KlS[0][krow][kphy] = pl;
  __syncthreads();
  int buf = 0;
  for (int ch = 0; ch < 64; ++ch) {
    if (ch < 63) {
      const size_t k0 = (size_t)(ch + 1) * 32;
      ph = *(const bf16x8*)&kh_p[(k0 + krow) * HD + kcol];
      pl = *(const bf16x8*)&kl_p[(k0 + krow) * HD + kcol];
    }
#pragma unroll
    for (int kt = 0; kt < 2; ++kt) {
      const int row = kt * 16 + c;
      bf16x8 kh0 = *(bf16x8*)&KhS[buf][row][pc0];
      bf16x8 kl0 = *(bf16x8*)&KlS[buf][row][pc0];
      bf16x8 kh1 = *(bf16x8*)&KhS[buf][row][pc1];
      bf16x8 kl1 = *(bf16x8*)&KlS[buf][row][pc1];
      f32x4 sc = zero;
      sc = MFMA(kh0, qf[0],  sc);
      sc = MFMA(kh0, qlf[0], sc);
      sc = MFMA(kl0, qf[0],  sc);
      sc = MFMA(kh1, qf[1],  sc);
      sc = MFMA(kh1, qlf[1], sc);
      sc = MFMA(kl1, qf[1],  sc);
      // 4 keys, same query: one shared rescale
      float cm = fmaxf(fmaxf(sc[0], sc[1]), fmaxf(sc[2], sc[3]));
      float nm = fmaxf(mr, cm);
      l1 = l1 * __expf(mr - nm) + __expf(sc[0] - nm) + __expf(sc[1] - nm)
                                + __expf(sc[2] - nm) + __expf(sc[3] - nm);
      mr = nm;
    }
    if (ch < 63) {
      *(bf16x8*)&KhS[buf ^ 1][krow][kphy] = ph;
      *(bf16x8*)&KlS[buf ^ 1][krow][kphy] = pl;
      __syncthreads();
      buf ^= 1;
    }
  }
  // merge (m, L1) across the 4 quads (lanes c, c+16, c+32, c+48)
#pragma unroll
  for (int off = 16; off < 64; off <<= 1) {
    float mo = __shfl_xor(mr, off, 64);
    float lo = __shfl_xor(l1, off, 64);
    float nm = fmaxf(mr, mo);
    l1 = l1 * __expf(mr - nm) + lo * __expf(mo - nm);
    mr = nm;
  }
  const float inv1 = 1.f / l1;

  f32x4 oacc[4]; oacc[0] = zero; oacc[1] = zero; oacc[2] = zero; oacc[3] = zero;
  float l2 = 0.f;

  // ================= pass 2: t = exp(attn1), o += t*V =================
  ph = *(const bf16x8*)&kh_p[(size_t)krow * HD + kcol];
  pl = *(const bf16x8*)&kl_p[(size_t)krow * HD + kcol];
  pv = *(const bf16x8*)&vt_p[(size_t)vrow * SEQ + vcol];
  *(bf16x8*)&KhS[0][krow][kphy] = ph;
  *(bf16x8*)&KlS[0][krow][kphy] = pl;
  *(bf16x8*)&VtS[0][vrow][vphy] = pv;
  __syncthreads();
  buf = 0;
  for (int ch = 0; ch < 64; ++ch) {
    if (ch < 63) {
      const size_t k0 = (size_t)(ch + 1) * 32;
      ph = *(const bf16x8*)&kh_p[(k0 + krow) * HD + kcol];
      pl = *(const bf16x8*)&kl_p[(k0 + krow) * HD + kcol];
      pv = *(const bf16x8*)&vt_p[(size_t)vrow * SEQ + k0 + vcol];
    }
#pragma unroll
    for (int kt = 0; kt < 2; ++kt) {
      const int row = kt * 16 + c;
      bf16x8 kh0 = *(bf16x8*)&KhS[buf][row][pc0];
      bf16x8 kl0 = *(bf16x8*)&KlS[buf][row][pc0];
      bf16x8 kh1 = *(bf16x8*)&KhS[buf][row][pc1];
      bf16x8 kl1 = *(bf16x8*)&KlS[buf][row][pc1];
      f32x4 sc = zero;
      sc = MFMA(kh0, qf[0],  sc);
      sc = MFMA(kh0, qlf[0], sc);
      sc = MFMA(kl0, qf[0],  sc);
      sc = MFMA(kh1, qf[1],  sc);
      sc = MFMA(kh1, qlf[1], sc);
      sc = MFMA(kl1, qf[1],  sc);
      bf16x4 t4;
      float ls = 0.f;
#pragma unroll
      for (int r = 0; r < 4; ++r) {
        float a1 = __expf(sc[r] - mr) * inv1;   // attn1 in [0,1]
        float tv = __expf(a1);                  // t in [1,e]
        ls += tv;
        t4[r] = (bf16)tv;
      }
      l2 += ls;
      *(bf16x4*)&tls[wave][c][kt * 16 + quad * 4] = t4;  // t^T[q][key] b64
    }
    // per-wave LDS round-trip (DS ops wave-ordered; no barrier)
    bf16x8 tb = *(bf16x8*)&tls[wave][c][quad * 8];       // B-frag: k=quad*8+j
#pragma unroll
    for (int dt = 0; dt < 4; ++dt) {
      bf16x8 va = *(bf16x8*)&VtS[buf][dt * 16 + c][vpc]; // A-frag: m=d, k=key
      oacc[dt] = MFMA(va, tb, oacc[dt]);
    }
    if (ch < 63) {
      *(bf16x8*)&KhS[buf ^ 1][krow][kphy] = ph;
      *(bf16x8*)&KlS[buf ^ 1][krow][kphy] = pl;
      *(bf16x8*)&VtS[buf ^ 1][vrow][vphy] = pv;
      __syncthreads();
      buf ^= 1;
    }
  }

  // merge L2 across quads
#pragma unroll
  for (int off = 16; off < 64; off <<= 1) l2 += __shfl_xor(l2, off, 64);

  // write O^T regs: lane (c,quad) reg (dt,r) holds o[q=q0+c][d=dt*16+quad*4+r]
  const int b = bh >> 3, h = bh & 7;
  const float rcp = 1.f / l2;
  bf16* orow = &((bf16*)O)[((size_t)b * SEQ + q0 + c) * EMB + h * HD];
#pragma unroll
  for (int dt = 0; dt < 4; ++dt) {
    bf16x4 ov;
#pragma unroll
    for (int r = 0; r < 4; ++r) ov[r] = (bf16)(oacc[dt][r] * rcp);
    *(bf16x4*)&orow[dt * 16 + quad * 4] = ov;
  }
}

// ---------------------------------------------------------------------------
extern "C" void kernel_launch(void* const* d_in, const int* in_sizes, int n_in,
                              void* d_out, int out_size, void* d_ws, size_t ws_size,
                              hipStream_t stream) {
  const float* x    = (const float*)d_in[0];
  const float* Wqkv = (const float*)d_in[1];
  const float* bqkv = (const float*)d_in[2];
  const float* Wout = (const float*)d_in[3];
  const float* bout = (const float*)d_in[4];
  float* out = (float*)d_out;

  char* ws = (char*)d_ws;
  const size_t SZ = (size_t)32 * SEQ * HD * 2;  // 8 MB per array
  bf16* Qh = (bf16*)(ws + 0 * SZ);
  bf16* Ql = (bf16*)(ws + 1 * SZ);
  bf16* Kh = (bf16*)(ws + 2 * SZ);
  bf16* Kl = (bf16*)(ws + 3 * SZ);
  bf16* Vt = (bf16*)(ws + 4 * SZ);
  bf16* O  = (bf16*)(ws + 5 * SZ);

  gemm_qkv<<<dim3(128, 24), 256, 0, stream>>>(x, Wqkv, bqkv, Qh, Ql, Kh, Kl, Vt);
  attn_kernel<<<dim3(32, SEQ / 64), 256, 0, stream>>>(Qh, Ql, Kh, Kl, Vt, O);
  gemm_out<<<dim3(128, 8), 256, 0, stream>>>(O, Wout, bout, out);
}

// Round 8
// 283.736 us; speedup vs baseline: 3.0740x; 1.0790x over previous
//
#include <hip/hip_runtime.h>

typedef __bf16 bf16;
typedef __attribute__((ext_vector_type(4))) __bf16 bf16x4;
typedef __attribute__((ext_vector_type(8))) __bf16 bf16x8;
typedef __attribute__((ext_vector_type(4))) float f32x4;

#define MFMA(A,B,C) __builtin_amdgcn_mfma_f32_16x16x32_bf16(A,B,C,0,0,0)

#define SEQ 2048
#define EMB 512
#define HD  64
#define SCALE 22.627416997969522f  // sqrt(512): scores are divided by E^-0.5
// Online-softmax seed: not -inf (fast-math folds inf constants to poison).
#define NEG_SEED -3.0e4f

// ---------------------------------------------------------------------------
// QKV projection: fp32 in, hi/lo split MFMA. XCD-stripe swizzle: each XCD
// (linear%8) owns a contiguous 1024-row m-stripe; within an XCD the m-block
// varies fastest -> per-XCD L2 working set = A-slice 2.1MB + W 3MB (resident).
// ---------------------------------------------------------------------------
__global__ __launch_bounds__(256)
void gemm_qkv(const float* __restrict__ A, const float* __restrict__ Bm,
              const float* __restrict__ bias,
              bf16* __restrict__ Qh, bf16* __restrict__ Ql,
              bf16* __restrict__ Kh, bf16* __restrict__ Kl,
              bf16* __restrict__ Vt) {
  __shared__ __align__(16) bf16 Ah[64][72], Al[64][72];
  __shared__ __align__(16) bf16 Bh[64][72], Bl[64][72];
  const int tid  = threadIdx.x;
  const int lane = tid & 63, wave = tid >> 6;
  // XCD-stripe swizzle (3072 blocks = 8 stripes x 16 m-blocks x 24 n-tiles)
  const int lin = blockIdx.x + gridDim.x * blockIdx.y;
  const int xcd = lin & 7;
  const int w_  = lin >> 3;                  // 0..383
  const int m0 = ((w_ & 15) + xcd * 16) * 64;
  const int n0 = (w_ >> 4) * 64;
  const int wm = (wave >> 1) * 32, wn = (wave & 1) * 32;
  const int c = lane & 15, quad = lane >> 4;
  const int fr = tid >> 4, fc = (tid & 15) * 4;

  const f32x4 zero = {0.f, 0.f, 0.f, 0.f};
  f32x4 acc[2][2];
  acc[0][0] = zero; acc[0][1] = zero; acc[1][0] = zero; acc[1][1] = zero;

  for (int k0 = 0; k0 < 512; k0 += 64) {
#pragma unroll
    for (int rr = 0; rr < 4; ++rr) {
      const int row = rr * 16 + fr;
      f32x4 av = *(const f32x4*)&A [(size_t)(m0 + row) * 512 + k0 + fc];
      f32x4 bv = *(const f32x4*)&Bm[(size_t)(n0 + row) * 512 + k0 + fc];
      bf16x4 ah, al, bh, bl;
#pragma unroll
      for (int j = 0; j < 4; ++j) {
        bf16 h = (bf16)av[j]; ah[j] = h; al[j] = (bf16)(av[j] - (float)h);
        bf16 g = (bf16)bv[j]; bh[j] = g; bl[j] = (bf16)(bv[j] - (float)g);
      }
      *(bf16x4*)&Ah[row][fc] = ah; *(bf16x4*)&Al[row][fc] = al;
      *(bf16x4*)&Bh[row][fc] = bh; *(bf16x4*)&Bl[row][fc] = bl;
    }
    __syncthreads();
#pragma unroll
    for (int ks = 0; ks < 64; ks += 32) {
      bf16x8 ah0 = *(bf16x8*)&Ah[wm + c     ][ks + quad * 8];
      bf16x8 ah1 = *(bf16x8*)&Ah[wm + 16 + c][ks + quad * 8];
      bf16x8 al0 = *(bf16x8*)&Al[wm + c     ][ks + quad * 8];
      bf16x8 al1 = *(bf16x8*)&Al[wm + 16 + c][ks + quad * 8];
      bf16x8 bh0 = *(bf16x8*)&Bh[wn + c     ][ks + quad * 8];
      bf16x8 bh1 = *(bf16x8*)&Bh[wn + 16 + c][ks + quad * 8];
      bf16x8 bl0 = *(bf16x8*)&Bl[wn + c     ][ks + quad * 8];
      bf16x8 bl1 = *(bf16x8*)&Bl[wn + 16 + c][ks + quad * 8];
      acc[0][0] = MFMA(ah0, bh0, acc[0][0]);
      acc[0][0] = MFMA(al0, bh0, acc[0][0]);
      acc[0][0] = MFMA(ah0, bl0, acc[0][0]);
      acc[0][1] = MFMA(ah0, bh1, acc[0][1]);
      acc[0][1] = MFMA(al0, bh1, acc[0][1]);
      acc[0][1] = MFMA(ah0, bl1, acc[0][1]);
      acc[1][0] = MFMA(ah1, bh0, acc[1][0]);
      acc[1][0] = MFMA(al1, bh0, acc[1][0]);
      acc[1][0] = MFMA(ah1, bl0, acc[1][0]);
      acc[1][1] = MFMA(ah1, bh1, acc[1][1]);
      acc[1][1] = MFMA(al1, bh1, acc[1][1]);
      acc[1][1] = MFMA(ah1, bl1, acc[1][1]);
    }
    __syncthreads();
  }

#pragma unroll
  for (int mt = 0; mt < 2; ++mt) {
#pragma unroll
    for (int nt = 0; nt < 2; ++nt) {
      const int n = n0 + wn + nt * 16 + c;
      const float bv = bias[n];
#pragma unroll
      for (int r = 0; r < 4; ++r) {
        const int m = m0 + wm + mt * 16 + quad * 4 + r;
        float v = acc[mt][nt][r] + bv;
        const int h = n / 192, t = n % 192;
        const size_t bh = (size_t)((m >> 11) * 8 + h);
        const int s = m & 2047;
        if (t < 64) {
          float q = v * SCALE;
          bf16 hi = (bf16)q;
          float lo = q - (float)hi;
          size_t idx = (bh * SEQ + s) * HD + t;
          Qh[idx] = hi; Ql[idx] = (bf16)lo;
        } else if (t < 128) {
          bf16 hi = (bf16)v;
          float lo = v - (float)hi;
          size_t idx = (bh * SEQ + s) * HD + (t - 64);
          Kh[idx] = hi; Kl[idx] = (bf16)lo;
        } else {
          Vt[(bh * HD + (t - 128)) * SEQ + s] = (bf16)v;
        }
      }
    }
  }
}

// ---------------------------------------------------------------------------
// Output projection: fp32 out. Same XCD-stripe swizzle (1024 blocks).
// ---------------------------------------------------------------------------
__global__ __launch_bounds__(256)
void gemm_out(const bf16* __restrict__ A, const float* __restrict__ Bm,
              const float* __restrict__ bias, float* __restrict__ C) {
  __shared__ __align__(16) bf16 As[64][72];
  __shared__ __align__(16) bf16 Bs[64][72];
  const int tid  = threadIdx.x;
  const int lane = tid & 63, wave = tid >> 6;
  const int lin = blockIdx.x + gridDim.x * blockIdx.y;
  const int xcd = lin & 7;
  const int w_  = lin >> 3;                  // 0..127
  const int m0 = ((w_ & 15) + xcd * 16) * 64;
  const int n0 = (w_ >> 4) * 64;
  const int wm = (wave >> 1) * 32, wn = (wave & 1) * 32;
  const int c = lane & 15, quad = lane >> 4;
  const int lr = tid >> 3, lc = (tid & 7) * 8;
  const int fr = tid >> 4, fc = (tid & 15) * 4;

  const f32x4 zero = {0.f, 0.f, 0.f, 0.f};
  f32x4 acc[2][2];
  acc[0][0] = zero; acc[0][1] = zero; acc[1][0] = zero; acc[1][1] = zero;

  for (int k0 = 0; k0 < 512; k0 += 64) {
    *(bf16x8*)&As[lr][lc]      = *(const bf16x8*)&A[(size_t)(m0 + lr     ) * 512 + k0 + lc];
    *(bf16x8*)&As[lr + 32][lc] = *(const bf16x8*)&A[(size_t)(m0 + lr + 32) * 512 + k0 + lc];
#pragma unroll
    for (int rr = 0; rr < 4; ++rr) {
      const int row = rr * 16 + fr;
      f32x4 bv = *(const f32x4*)&Bm[(size_t)(n0 + row) * 512 + k0 + fc];
      bf16x4 bb;
#pragma unroll
      for (int j = 0; j < 4; ++j) bb[j] = (bf16)bv[j];
      *(bf16x4*)&Bs[row][fc] = bb;
    }
    __syncthreads();
#pragma unroll
    for (int ks = 0; ks < 64; ks += 32) {
      bf16x8 a0 = *(bf16x8*)&As[wm + c     ][ks + quad * 8];
      bf16x8 a1 = *(bf16x8*)&As[wm + 16 + c][ks + quad * 8];
      bf16x8 b0 = *(bf16x8*)&Bs[wn + c     ][ks + quad * 8];
      bf16x8 b1 = *(bf16x8*)&Bs[wn + 16 + c][ks + quad * 8];
      acc[0][0] = MFMA(a0, b0, acc[0][0]);
      acc[0][1] = MFMA(a0, b1, acc[0][1]);
      acc[1][0] = MFMA(a1, b0, acc[1][0]);
      acc[1][1] = MFMA(a1, b1, acc[1][1]);
    }
    __syncthreads();
  }

#pragma unroll
  for (int mt = 0; mt < 2; ++mt) {
#pragma unroll
    for (int nt = 0; nt < 2; ++nt) {
      const int n = n0 + wn + nt * 16 + c;
      const float bv = bias[n];
#pragma unroll
      for (int r = 0; r < 4; ++r) {
        const int m = m0 + wm + mt * 16 + quad * 4 + r;
        C[(size_t)m * 512 + n] = acc[mt][nt][r] + bv;
      }
    }
  }
}

// ---------------------------------------------------------------------------
// Attention, double softmax, S^T orientation + SPARSE EXP:
//  pass 1: skip l1 update when chunk max < m-90 (exp underflows to 0 exactly,
//          same as the fp32 reference).
//  pass 2: skip exp/t when chunk max < m-18: a1 < e^-18 < 2^-24 so
//          fl(exp(a1)) == 1.0f exactly -> t = 1, l2 += 4. Bit-identical.
// Scores ~N(0,181^2): per query only ~1 chunk is pass-2-active -> ~97% of the
// exp chains vanish.
// ---------------------------------------------------------------------------
__global__ __launch_bounds__(256, 4)
void attn_kernel(const bf16* __restrict__ Qh, const bf16* __restrict__ Ql,
                 const bf16* __restrict__ Kh, const bf16* __restrict__ Kl,
                 const bf16* __restrict__ Vt, bf16* __restrict__ O) {
  __shared__ __align__(16) bf16 KhS[2][32][64];  // [key][d], chunk^=(row&7)
  __shared__ __align__(16) bf16 KlS[2][32][64];
  __shared__ __align__(16) bf16 VtS[2][64][32];  // [d][key], chunk^=(row&3)
  __shared__ __align__(16) bf16 tls[4][16][40];  // per-wave t^T[q][key], +8 pad
  const int tid  = threadIdx.x;
  const int lane = tid & 63, wave = tid >> 6;
  const int c = lane & 15, quad = lane >> 4;
  const int bh = blockIdx.x;                     // XCD swizzle: head-major
  const int q0 = blockIdx.y * 64 + wave * 16;
  const size_t hoff = (size_t)bh * SEQ * HD;
  const bf16* qh_p = Qh + hoff;
  const bf16* ql_p = Ql + hoff;
  const bf16* kh_p = Kh + hoff;
  const bf16* kl_p = Kl + hoff;
  const bf16* vt_p = Vt + hoff;                  // [HD][SEQ]
  const f32x4 zero = {0.f, 0.f, 0.f, 0.f};

  const int krow = tid >> 3;
  const int kcol = (tid & 7) * 8;
  const int kphy = ((tid & 7) ^ (krow & 7)) * 8;
  const int vrow = tid >> 2;
  const int vcol = (tid & 3) * 8;
  const int vphy = ((tid & 3) ^ (vrow & 3)) * 8;
  const int pc0 = ((0 + quad) ^ (c & 7)) * 8;
  const int pc1 = ((4 + quad) ^ (c & 7)) * 8;
  const int vpc = (quad ^ (c & 3)) * 8;

  bf16x8 qf[2], qlf[2];
#pragma unroll
  for (int t = 0; t < 2; ++t) {
    size_t off = (size_t)(q0 + c) * HD + t * 32 + quad * 8;
    qf[t]  = *(const bf16x8*)&qh_p[off];
    qlf[t] = *(const bf16x8*)&ql_p[off];
  }

  float mr = NEG_SEED, l1 = 0.f;

  // ================= pass 1: online (m, L1), sparse =================
  bf16x8 ph, pl, pv;
  ph = *(const bf16x8*)&kh_p[(size_t)krow * HD + kcol];
  pl = *(const bf16x8*)&kl_p[(size_t)krow * HD + kcol];
  *(bf16x8*)&KhS[0][krow][kphy] = ph;
  *(bf16x8*)&KlS[0][krow][kphy] = pl;
  __syncthreads();
  int buf = 0;
  for (int ch = 0; ch < 64; ++ch) {
    if (ch < 63) {
      const size_t k0 = (size_t)(ch + 1) * 32;
      ph = *(const bf16x8*)&kh_p[(k0 + krow) * HD + kcol];
      pl = *(const bf16x8*)&kl_p[(k0 + krow) * HD + kcol];
    }
#pragma unroll
    for (int kt = 0; kt < 2; ++kt) {
      const int row = kt * 16 + c;
      bf16x8 kh0 = *(bf16x8*)&KhS[buf][row][pc0];
      bf16x8 kl0 = *(bf16x8*)&KlS[buf][row][pc0];
      bf16x8 kh1 = *(bf16x8*)&KhS[buf][row][pc1];
      bf16x8 kl1 = *(bf16x8*)&KlS[buf][row][pc1];
      f32x4 sc = zero;
      sc = MFMA(kh0, qf[0],  sc);
      sc = MFMA(kh0, qlf[0], sc);
      sc = MFMA(kl0, qf[0],  sc);
      sc = MFMA(kh1, qf[1],  sc);
      sc = MFMA(kh1, qlf[1], sc);
      sc = MFMA(kl1, qf[1],  sc);
      float cm = fmaxf(fmaxf(sc[0], sc[1]), fmaxf(sc[2], sc[3]));
      if (cm > mr - 90.f) {   // else: all exp(s-m) underflow to 0 exactly
        float nm = fmaxf(mr, cm);
        l1 = l1 * __expf(mr - nm) + __expf(sc[0] - nm) + __expf(sc[1] - nm)
                                  + __expf(sc[2] - nm) + __expf(sc[3] - nm);
        mr = nm;
      }
    }
    if (ch < 63) {
      *(bf16x8*)&KhS[buf ^ 1][krow][kphy] = ph;
      *(bf16x8*)&KlS[buf ^ 1][krow][kphy] = pl;
      __syncthreads();
      buf ^= 1;
    }
  }
#pragma unroll
  for (int off = 16; off < 64; off <<= 1) {
    float mo = __shfl_xor(mr, off, 64);
    float lo = __shfl_xor(l1, off, 64);
    float nm = fmaxf(mr, mo);
    l1 = l1 * __expf(mr - nm) + lo * __expf(mo - nm);
    mr = nm;
  }
  const float inv1 = 1.f / l1;

  f32x4 oacc[4]; oacc[0] = zero; oacc[1] = zero; oacc[2] = zero; oacc[3] = zero;
  float l2 = 0.f;

  // ================= pass 2: t = exp(attn1), o += t*V, sparse =========
  ph = *(const bf16x8*)&kh_p[(size_t)krow * HD + kcol];
  pl = *(const bf16x8*)&kl_p[(size_t)krow * HD + kcol];
  pv = *(const bf16x8*)&vt_p[(size_t)vrow * SEQ + vcol];
  *(bf16x8*)&KhS[0][krow][kphy] = ph;
  *(bf16x8*)&KlS[0][krow][kphy] = pl;
  *(bf16x8*)&VtS[0][vrow][vphy] = pv;
  __syncthreads();
  buf = 0;
  for (int ch = 0; ch < 64; ++ch) {
    if (ch < 63) {
      const size_t k0 = (size_t)(ch + 1) * 32;
      ph = *(const bf16x8*)&kh_p[(k0 + krow) * HD + kcol];
      pl = *(const bf16x8*)&kl_p[(k0 + krow) * HD + kcol];
      pv = *(const bf16x8*)&vt_p[(size_t)vrow * SEQ + k0 + vcol];
    }
#pragma unroll
    for (int kt = 0; kt < 2; ++kt) {
      const int row = kt * 16 + c;
      bf16x8 kh0 = *(bf16x8*)&KhS[buf][row][pc0];
      bf16x8 kl0 = *(bf16x8*)&KlS[buf][row][pc0];
      bf16x8 kh1 = *(bf16x8*)&KhS[buf][row][pc1];
      bf16x8 kl1 = *(bf16x8*)&KlS[buf][row][pc1];
      f32x4 sc = zero;
      sc = MFMA(kh0, qf[0],  sc);
      sc = MFMA(kh0, qlf[0], sc);
      sc = MFMA(kl0, qf[0],  sc);
      sc = MFMA(kh1, qf[1],  sc);
      sc = MFMA(kh1, qlf[1], sc);
      sc = MFMA(kl1, qf[1],  sc);
      float cm = fmaxf(fmaxf(sc[0], sc[1]), fmaxf(sc[2], sc[3]));
      bf16x4 t4;
      if (cm > mr - 18.f) {
        // active: a1 may exceed 2^-24 -> compute exactly
        float ls = 0.f;
#pragma unroll
        for (int r = 0; r < 4; ++r) {
          float a1 = __expf(sc[r] - mr) * inv1;  // attn1 in [0,1]
          float tv = __expf(a1);                 // t in [1,e]
          ls += tv;
          t4[r] = (bf16)tv;
        }
        l2 += ls;
      } else {
        // a1 < e^-18 < 2^-24: fl(exp(a1)) == 1.0f exactly
        t4[0] = t4[1] = t4[2] = t4[3] = (bf16)1.0f;
        l2 += 4.f;
      }
      *(bf16x4*)&tls[wave][c][kt * 16 + quad * 4] = t4;
    }
    bf16x8 tb = *(bf16x8*)&tls[wave][c][quad * 8];
#pragma unroll
    for (int dt = 0; dt < 4; ++dt) {
      bf16x8 va = *(bf16x8*)&VtS[buf][dt * 16 + c][vpc];
      oacc[dt] = MFMA(va, tb, oacc[dt]);
    }
    if (ch < 63) {
      *(bf16x8*)&KhS[buf ^ 1][krow][kphy] = ph;
      *(bf16x8*)&KlS[buf ^ 1][krow][kphy] = pl;
      *(bf16x8*)&VtS[buf ^ 1][vrow][vphy] = pv;
      __syncthreads();
      buf ^= 1;
    }
  }

#pragma unroll
  for (int off = 16; off < 64; off <<= 1) l2 += __shfl_xor(l2, off, 64);

  const int b = bh >> 3, h = bh & 7;
  const float rcp = 1.f / l2;
  bf16* orow = &((bf16*)O)[((size_t)b * SEQ + q0 + c) * EMB + h * HD];
#pragma unroll
  for (int dt = 0; dt < 4; ++dt) {
    bf16x4 ov;
#pragma unroll
    for (int r = 0; r < 4; ++r) ov[r] = (bf16)(oacc[dt][r] * rcp);
    *(bf16x4*)&orow[dt * 16 + quad * 4] = ov;
  }
}

// ---------------------------------------------------------------------------
extern "C" void kernel_launch(void* const* d_in, const int* in_sizes, int n_in,
                              void* d_out, int out_size, void* d_ws, size_t ws_size,
                              hipStream_t stream) {
  const float* x    = (const float*)d_in[0];
  const float* Wqkv = (const float*)d_in[1];
  const float* bqkv = (const float*)d_in[2];
  const float* Wout = (const float*)d_in[3];
  const float* bout = (const float*)d_in[4];
  float* out = (float*)d_out;

  char* ws = (char*)d_ws;
  const size_t SZ = (size_t)32 * SEQ * HD * 2;  // 8 MB per array
  bf16* Qh = (bf16*)(ws + 0 * SZ);
  bf16* Ql = (bf16*)(ws + 1 * SZ);
  bf16* Kh = (bf16*)(ws + 2 * SZ);
  bf16* Kl = (bf16*)(ws + 3 * SZ);
  bf16* Vt = (bf16*)(ws + 4 * SZ);
  bf16* O  = (bf16*)(ws + 5 * SZ);

  gemm_qkv<<<dim3(128, 24), 256, 0, stream>>>(x, Wqkv, bqkv, Qh, Ql, Kh, Kl, Vt);
  attn_kernel<<<dim3(32, SEQ / 64), 256, 0, stream>>>(Qh, Ql, Kh, Kl, Vt, O);
  gemm_out<<<dim3(128, 8), 256, 0, stream>>>(O, Wout, bout, out);
}